// Round 5
// baseline (438.618 us; speedup 1.0000x reference)
//
#include <hip/hip_runtime.h>

constexpr int T  = 168;
constexpr int P  = 16;
constexpr int H  = 24;
constexpr int R  = 4;      // batch rows per workgroup
constexpr int K2 = 24;     // unified inner-K for both layers (x zero-padded 16->24)

__device__ __forceinline__ float rcp_f(float x) { return __builtin_amdgcn_rcpf(x); }
__device__ __forceinline__ float sigm_f(float x) { return rcp_f(1.f + __expf(-x)); }
// tanh(x) = 2*sigmoid(2x) - 1
__device__ __forceinline__ float tanh_fast(float x) {
    return fmaf(2.f, rcp_f(1.f + __expf(-2.f * x)), -1.f);
}
// Intra-wave LDS write->read ordering + compiler reorder fence.
#define LDS_SYNC() asm volatile("s_waitcnt lgkmcnt(0)" ::: "memory")

// Workgroup = 2 waves x R rows, producer/consumer:
//   wave 0 (ph=0): layer-1 for steps 0..T-1, consuming x (staged in LDS),
//                  producing tanh(h1) into t1b double-buffer.
//   wave 1 (ph=1): layer-2 for steps 0..T-1, lagging one step, consuming t1b,
//                  then the FC head.
// Both waves run the SAME gate-compute code with the SAME register arrays
// (wa/wb, 96 floats) loaded from different weight matrices -> live weight set
// is 96 not 176, fitting arch VGPRs and killing the R4 AGPR-read tax.
// One __syncthreads per step; all other comms intra-wave (shfl / wave-sync LDS).
__global__ __attribute__((amdgpu_flat_work_group_size(128, 128),
                          amdgpu_waves_per_eu(2, 2)))
void lstm2_pipe(const float* __restrict__ x,
                const float* __restrict__ Wih1, const float* __restrict__ Whh1,
                const float* __restrict__ bih1, const float* __restrict__ bhh1,
                const float* __restrict__ Wih2, const float* __restrict__ Whh2,
                const float* __restrict__ bih2, const float* __restrict__ bhh2,
                const float* __restrict__ W1, const float* __restrict__ b1,
                const float* __restrict__ W2, const float* __restrict__ b2,
                float* __restrict__ out)
{
    const int tid  = threadIdx.x;
    const int ph   = tid >> 6;            // 0: layer-1 wave, 1: layer-2 wave
    const int lane = tid & 63;
    const int s    = (lane < 48) ? lane : 47;   // clamp idle lanes
    const int u    = s % H;                      // unit 0..23
    const int half = s / H;                      // 0: {i,g}, 1: {f,o}
    const int q0   = half * H + u;               // i or f gate row
    const int q1   = (2 + half) * H + u;         // g or o gate row
    const int row0 = blockIdx.x * R;

    __shared__ __align__(16) float xbuf[2][R][32];  // staged x, [16..31] zero pad
    __shared__ __align__(16) float t1b [2][R][32];  // wave0 out: tanh(h1)
    __shared__ __align__(16) float t2b [2][R][32];  // wave1 out: tanh(h2) (head uses parity T&1=0)
    __shared__ __align__(16) float h1s [R][32];     // wave0-private h1 state
    __shared__ __align__(16) float h2s [R][32];     // wave1-private h2 state
    __shared__ __align__(16) float hd  [R][16];     // head fc1 scratch

    // ---- unified weight registers: 96 floats (live set fits arch VGPRs) ----
    float wa0[K2], wa1[K2];   // in1-weights for gate rows q0, q1
    float wb0[K2], wb1[K2];   // in2(h)-weights for gate rows q0, q1
    float bi0, bi1;
    if (ph == 0) {
        #pragma unroll
        for (int k = 0; k < P / 4; ++k) {
            float4 a = ((const float4*)(Wih1 + q0 * P))[k];
            float4 b = ((const float4*)(Wih1 + q1 * P))[k];
            wa0[4*k] = a.x; wa0[4*k+1] = a.y; wa0[4*k+2] = a.z; wa0[4*k+3] = a.w;
            wa1[4*k] = b.x; wa1[4*k+1] = b.y; wa1[4*k+2] = b.z; wa1[4*k+3] = b.w;
        }
        #pragma unroll
        for (int k = P; k < K2; ++k) { wa0[k] = 0.f; wa1[k] = 0.f; }
        #pragma unroll
        for (int k = 0; k < H / 4; ++k) {
            float4 a = ((const float4*)(Whh1 + q0 * H))[k];
            float4 b = ((const float4*)(Whh1 + q1 * H))[k];
            wb0[4*k] = a.x; wb0[4*k+1] = a.y; wb0[4*k+2] = a.z; wb0[4*k+3] = a.w;
            wb1[4*k] = b.x; wb1[4*k+1] = b.y; wb1[4*k+2] = b.z; wb1[4*k+3] = b.w;
        }
        bi0 = bih1[q0] + bhh1[q0];
        bi1 = bih1[q1] + bhh1[q1];
    } else {
        #pragma unroll
        for (int k = 0; k < H / 4; ++k) {
            float4 a = ((const float4*)(Wih2 + q0 * H))[k];
            float4 b = ((const float4*)(Wih2 + q1 * H))[k];
            wa0[4*k] = a.x; wa0[4*k+1] = a.y; wa0[4*k+2] = a.z; wa0[4*k+3] = a.w;
            wa1[4*k] = b.x; wa1[4*k+1] = b.y; wa1[4*k+2] = b.z; wa1[4*k+3] = b.w;
        }
        #pragma unroll
        for (int k = 0; k < H / 4; ++k) {
            float4 a = ((const float4*)(Whh2 + q0 * H))[k];
            float4 b = ((const float4*)(Whh2 + q1 * H))[k];
            wb0[4*k] = a.x; wb0[4*k+1] = a.y; wb0[4*k+2] = a.z; wb0[4*k+3] = a.w;
            wb1[4*k] = b.x; wb1[4*k+1] = b.y; wb1[4*k+2] = b.z; wb1[4*k+3] = b.w;
        }
        bi0 = bih2[q0] + bhh2[q0];
        bi1 = bih2[q1] + bhh2[q1];
    }

    // ---- init: each wave zeros its own h-state; wave0 zeros xbuf pad + stages x(0)
    if (ph == 0) {
        if (lane < H) {
            #pragma unroll
            for (int r = 0; r < R; ++r) h1s[r][lane] = 0.f;
        }
        // zero pad slots xbuf[p][r][16..31]: 2*4*16 = 128 slots, 2 per lane
        for (int f = lane; f < 128; f += 64) {
            int p = f >> 6, rem = f & 63, r = rem >> 4, k = rem & 15;
            xbuf[p][r][16 + k] = 0.f;
        }
        // stage x(step 0) into parity 0
        {
            int rr = lane >> 4, kk = lane & 15;
            xbuf[0][rr][kk] = x[(size_t)(row0 + rr) * T * P + kk];
        }
    } else {
        if (lane < H) {
            #pragma unroll
            for (int r = 0; r < R; ++r) h2s[r][lane] = 0.f;
        }
    }
    __syncthreads();

    // per-wave source/dest LDS views (wave-uniform)
    const float* in1base = (ph == 0) ? &xbuf[0][0][0] : &t1b[0][0][0];
    float*       in2base = (ph == 0) ? &h1s[0][0]     : &h2s[0][0];
    float*       outbase = (ph == 0) ? &t1b[0][0][0]  : &t2b[0][0][0];

    float c[R];
    #pragma unroll
    for (int r = 0; r < R; ++r) c[r] = 0.f;

    for (int i = 0; i <= T; ++i) {
        // wave0 active for i in [0,T); wave1 for i in [1,T] (processing step i-1)
        if ((unsigned)(i - ph) < (unsigned)T) {
            const float* in1 = in1base + (size_t)((i + ph) & 1) * (R * 32);
            float*       tou = outbase + (size_t)(i & 1) * (R * 32);
            #pragma unroll
            for (int r = 0; r < R; ++r) {
                float g0 = bi0, g1 = bi1;
                #pragma unroll
                for (int k = 0; k < K2 / 4; ++k) {
                    float4 a = ((const float4*)(in1 + r * 32))[k];
                    float4 b = ((const float4*)(in2base + r * 32))[k];
                    g0 = fmaf(a.x, wa0[4*k],   g0);  g1 = fmaf(a.x, wa1[4*k],   g1);
                    g0 = fmaf(a.y, wa0[4*k+1], g0);  g1 = fmaf(a.y, wa1[4*k+1], g1);
                    g0 = fmaf(a.z, wa0[4*k+2], g0);  g1 = fmaf(a.z, wa1[4*k+2], g1);
                    g0 = fmaf(a.w, wa0[4*k+3], g0);  g1 = fmaf(a.w, wa1[4*k+3], g1);
                    g0 = fmaf(b.x, wb0[4*k],   g0);  g1 = fmaf(b.x, wb1[4*k],   g1);
                    g0 = fmaf(b.y, wb0[4*k+1], g0);  g1 = fmaf(b.y, wb1[4*k+1], g1);
                    g0 = fmaf(b.z, wb0[4*k+2], g0);  g1 = fmaf(b.z, wb1[4*k+2], g1);
                    g0 = fmaf(b.w, wb0[4*k+3], g0);  g1 = fmaf(b.w, wb1[4*k+3], g1);
                }
                // a0 = sigmoid(g0) [i|f]; a1 = tanh(g1) on half0 [g], sigmoid on half1 [o]
                float a0 = sigm_f(g0);
                float px = (half == 0) ? g1 + g1 : g1;
                float sv = sigm_f(px);
                float a1 = (half == 0) ? sv + sv - 1.f : sv;
                float fa = __shfl(a0, lane + 24);     // f-gate from upper half
                float oa = __shfl(a1, lane + 24);     // o-gate from upper half
                c[r] = fmaf(fa, c[r], a0 * a1);
                float hv = oa * tanh_fast(c[r]);
                float th = tanh_fast(hv);
                if (lane < H) {
                    *(in2base + r * 32 + lane) = hv;
                    *(tou     + r * 32 + lane) = th;
                }
            }
        }
        // wave0 stages x(i+1) for its next iteration (consumed after the barrier)
        if (ph == 0 && i + 1 < T) {
            int rr = lane >> 4, kk = lane & 15;
            xbuf[(i + 1) & 1][rr][kk] =
                x[(size_t)(row0 + rr) * T * P + (size_t)(i + 1) * P + kk];
        }
        __syncthreads();
    }

    // ---- head (wave 1): tanh(h2) already in t2b[0] (T even) -> fc1 relu -> fc2
    if (ph == 1) {
        float w1r[H];   // W1 row for this lane (lane<16)
        float w2r[16];  // W2 row for this lane (lane<24)
        if (lane < 16) {
            #pragma unroll
            for (int j = 0; j < H; ++j) w1r[j] = W1[lane * H + j];
        }
        if (lane < H) {
            #pragma unroll
            for (int j = 0; j < 16; ++j) w2r[j] = W2[lane * 16 + j];
        }
        #pragma unroll
        for (int r = 0; r < R; ++r) {
            if (lane < 16) {
                float acc = b1[lane];
                #pragma unroll
                for (int j = 0; j < H; ++j) acc = fmaf(t2b[0][r][j], w1r[j], acc);
                hd[r][lane] = fmaxf(acc, 0.f);
            }
            LDS_SYNC();
            if (lane < H) {
                float acc = b2[lane];
                #pragma unroll
                for (int j = 0; j < 16; ++j) acc = fmaf(hd[r][j], w2r[j], acc);
                out[(size_t)(row0 + r) * H + lane] = acc;
            }
            LDS_SYNC();
        }
    }
}

extern "C" void kernel_launch(void* const* d_in, const int* in_sizes, int n_in,
                              void* d_out, int out_size, void* d_ws, size_t ws_size,
                              hipStream_t stream)
{
    const float* x    = (const float*)d_in[0];
    const float* Wih1 = (const float*)d_in[1];
    const float* Whh1 = (const float*)d_in[2];
    const float* bih1 = (const float*)d_in[3];
    const float* bhh1 = (const float*)d_in[4];
    const float* Wih2 = (const float*)d_in[5];
    const float* Whh2 = (const float*)d_in[6];
    const float* bih2 = (const float*)d_in[7];
    const float* bhh2 = (const float*)d_in[8];
    const float* W1   = (const float*)d_in[9];
    const float* b1   = (const float*)d_in[10];
    const float* W2   = (const float*)d_in[11];
    const float* b2   = (const float*)d_in[12];
    float* out = (float*)d_out;

    const int B = in_sizes[0] / (T * P);             // 4096
    hipLaunchKernelGGL(lstm2_pipe, dim3(B / R), dim3(128), 0, stream,
                       x, Wih1, Whh1, bih1, bhh1, Wih2, Whh2, bih2, bhh2,
                       W1, b1, W2, b2, out);
}